// Round 1
// baseline (221.797 us; speedup 1.0000x reference)
//
#include <hip/hip_runtime.h>
#include <cstddef>

// Problem constants
// N=8, C=128, L=512, D=64, F=512, ATTN_W=64

// ---------------------------------------------------------------------------
// Kernel A: xt = transpose(x) ; q = xt@Wt ; k = xt@Wx
// grid 64 (= N * L/64), block 256. LDS tile of x[n, :, l0:l0+64].
// ---------------------------------------------------------------------------
__global__ __launch_bounds__(256) void qk_xt_kernel(
    const float* __restrict__ x, const float* __restrict__ Wx,
    const float* __restrict__ Wt, float* __restrict__ q,
    float* __restrict__ k, float* __restrict__ xt) {
  __shared__ float xs[128][65];  // [c][l], +1 pad: transposed reads conflict-free
  int tid = threadIdx.x;
  int n = blockIdx.x >> 3;
  int l0 = (blockIdx.x & 7) << 6;

  // load x tile: coalesced 64-float rows
  for (int idx = tid; idx < 128 * 64; idx += 256) {
    int c = idx >> 6, t = idx & 63;
    xs[c][t] = x[((size_t)n * 128 + c) * 512 + l0 + t];
  }
  __syncthreads();

  int l = tid & 63;             // lane = l -> conflict-free xs[c][l]
  int d0 = (tid >> 6) << 4;     // 16 d-values per thread
  float qa[16], ka[16];
#pragma unroll
  for (int i = 0; i < 16; i++) { qa[i] = 0.f; ka[i] = 0.f; }

  for (int cc = 0; cc < 128; cc++) {
    float xv = xs[cc][l];
    const float4* wq = (const float4*)(Wt + cc * 64 + d0);  // wave-uniform, L1-hit
    const float4* wk = (const float4*)(Wx + cc * 64 + d0);
#pragma unroll
    for (int v = 0; v < 4; v++) {
      float4 aq = wq[v], bk = wk[v];
      qa[4 * v + 0] += xv * aq.x; qa[4 * v + 1] += xv * aq.y;
      qa[4 * v + 2] += xv * aq.z; qa[4 * v + 3] += xv * aq.w;
      ka[4 * v + 0] += xv * bk.x; ka[4 * v + 1] += xv * bk.y;
      ka[4 * v + 2] += xv * bk.z; ka[4 * v + 3] += xv * bk.w;
    }
  }
  size_t rowbase = ((size_t)n * 512 + l0 + l) * 64 + d0;
#pragma unroll
  for (int v = 0; v < 4; v++) {
    ((float4*)(q + rowbase))[v] = make_float4(qa[4*v], qa[4*v+1], qa[4*v+2], qa[4*v+3]);
    ((float4*)(k + rowbase))[v] = make_float4(ka[4*v], ka[4*v+1], ka[4*v+2], ka[4*v+3]);
  }

  // write xt (N,L,C): coalesced over c
  for (int idx = tid; idx < 128 * 64; idx += 256) {
    int c = idx & 127, t = idx >> 7;
    xt[((size_t)n * 512 + l0 + t) * 128 + c] = xs[c][t];
  }
}

// ---------------------------------------------------------------------------
// Kernel B: banded additive-attention scores + softmax -> a (N,L,L) incl zeros
// grid 2048 (= N*L/2), block 128 (2 waves, 1 row per wave).
// In-band max is valid: denominator >= 1 so the full-row-max vs band-max
// difference only rescales eps=1e-6 -> error ~1e-5, far under threshold.
// ---------------------------------------------------------------------------
__global__ __launch_bounds__(128) void attn_kernel(
    const float* __restrict__ q, const float* __restrict__ k,
    const float* __restrict__ bh, const float* __restrict__ Wa,
    const float* __restrict__ ba, float* __restrict__ a) {
  __shared__ float ks[2][64][65];  // [wave][j_rel][d], +1 pad
  __shared__ float qs[2][64];
  __shared__ float was[64];
  __shared__ float av[2][64];
  int tid = threadIdx.x;
  int w = tid >> 6, lane = tid & 63;
  int row = blockIdx.x * 2 + w;
  int n = row >> 9, i = row & 511;

  if (tid < 64) was[tid] = Wa[tid];
  qs[w][lane] = q[((size_t)n * 512 + i) * 64 + lane] + bh[lane];

  int jlo = i - 32;
  for (int it = 0; it < 64; it++) {
    int j = jlo + it;
    ks[w][it][lane] = (j >= 0 && j < 512) ? k[((size_t)n * 512 + j) * 64 + lane] : 0.f;
  }
  __syncthreads();

  int j = jlo + lane;
  bool valid = (j >= 0 && j < 512);
  float e = 0.f;
#pragma unroll 8
  for (int d = 0; d < 64; d++) {
    float hx = qs[w][d] + ks[w][lane][d];
    // tanh(x) = 1 - 2/(exp(2x)+1); exact at +-inf, ~1e-6 rel error
    float ex2 = __expf(2.f * hx);
    float th = 1.f - 2.f * __builtin_amdgcn_rcpf(ex2 + 1.f);
    e += was[d] * th;
  }
  e += ba[0];
  if (!valid) e = -1e30f;

  float m = e;
  for (int o = 32; o > 0; o >>= 1) m = fmaxf(m, __shfl_xor(m, o, 64));
  float ex = valid ? __expf(e - m) : 0.f;
  float s = ex;
  for (int o = 32; o > 0; o >>= 1) s += __shfl_xor(s, o, 64);
  float aval = ex / (s + 1e-6f);

  av[w][lane] = aval;
  __syncthreads();

  float* arow = a + ((size_t)n * 512 + i) * 512;
  for (int cb = 0; cb < 512; cb += 64) {
    int col = cb + lane;
    int jr = col - jlo;
    arow[col] = (jr >= 0 && jr < 64) ? av[w][jr] : 0.f;
  }
}

// ---------------------------------------------------------------------------
// Kernel C: v = a @ xt (banded), x2 = LN0(v + xt)
// grid 4096 (= N*L), block 128 (= C).
// ---------------------------------------------------------------------------
__global__ __launch_bounds__(128) void av_ln_kernel(
    const float* __restrict__ a, const float* __restrict__ xt,
    const float* __restrict__ g0, const float* __restrict__ be0,
    float* __restrict__ x2) {
  __shared__ float as[64];
  __shared__ float red[4];
  int row = blockIdx.x;
  int n = row >> 9, i = row & 511;
  int c = threadIdx.x;
  int jlo = i - 32;

  if (c < 64) {
    int j = jlo + c;
    as[c] = (j >= 0 && j < 512) ? a[((size_t)n * 512 + i) * 512 + j] : 0.f;
  }
  __syncthreads();

  const float* xtn = xt + (size_t)n * 512 * 128;
  float acc = 0.f;
#pragma unroll 8
  for (int jr = 0; jr < 64; jr++) {
    int jc = min(max(jlo + jr, 0), 511);   // as[jr]==0 when out of range
    acc += as[jr] * xtn[jc * 128 + c];
  }
  float y = acc + xtn[i * 128 + c];

  float s = y, s2 = y * y;
  for (int o = 32; o > 0; o >>= 1) {
    s += __shfl_xor(s, o, 64);
    s2 += __shfl_xor(s2, o, 64);
  }
  int wid = c >> 6;
  if ((c & 63) == 0) { red[wid * 2] = s; red[wid * 2 + 1] = s2; }
  __syncthreads();
  float S = red[0] + red[2], S2 = red[1] + red[3];
  float mu = S * (1.f / 128.f);
  float var = S2 * (1.f / 128.f) - mu * mu;
  float rs = rsqrtf(var + 1e-5f);
  x2[(size_t)row * 128 + c] = (y - mu) * rs * g0[c] + be0[c];
}

// ---------------------------------------------------------------------------
// Kernel D: FFN (x2@W0+b0 -> relu -> @W1+b1) + residual + LN1 -> x4 (N,L,C)
// grid 512 (8 rows/block to amortize W0/W1 traffic), block 256.
// ---------------------------------------------------------------------------
__global__ __launch_bounds__(256) void ffn_ln_kernel(
    const float* __restrict__ x2, const float* __restrict__ W0,
    const float* __restrict__ b0, const float* __restrict__ W1,
    const float* __restrict__ b1, const float* __restrict__ g1,
    const float* __restrict__ be1, float* __restrict__ x4) {
  __shared__ float xs[8][128];
  __shared__ float ts[8][512];
  __shared__ float ys[8][128];
  int tid = threadIdx.x;
  size_t rbase = (size_t)blockIdx.x * 8;

  for (int idx = tid; idx < 8 * 128; idx += 256) {
    int r = idx >> 7, c = idx & 127;
    xs[r][c] = x2[(rbase + r) * 128 + c];
  }
  __syncthreads();

  // GEMM1 + relu: each thread does 2 f-columns for all 8 rows
  for (int f = tid; f < 512; f += 256) {
    float bb = b0[f];
    float acc[8];
#pragma unroll
    for (int r = 0; r < 8; r++) acc[r] = bb;
    for (int cc = 0; cc < 128; cc++) {
      float wv = W0[cc * 512 + f];  // coalesced across lanes
#pragma unroll
      for (int r = 0; r < 8; r++) acc[r] += xs[r][cc] * wv;  // LDS broadcast
    }
#pragma unroll
    for (int r = 0; r < 8; r++) ts[r][f] = fmaxf(acc[r], 0.f);
  }
  __syncthreads();

  // GEMM2: thread (rg, c) does 4 rows x 1 column
  {
    int c = tid & 127, rg = tid >> 7;
    float bb = b1[c];
    float acc[4];
#pragma unroll
    for (int r = 0; r < 4; r++) acc[r] = bb;
    for (int f = 0; f < 512; f++) {
      float wv = W1[f * 128 + c];  // coalesced
#pragma unroll
      for (int r = 0; r < 4; r++) acc[r] += ts[rg * 4 + r][f] * wv;  // broadcast
    }
#pragma unroll
    for (int r = 0; r < 4; r++) ys[rg * 4 + r][c] = acc[r] + xs[rg * 4 + r][c];
  }
  __syncthreads();

  // LN1 per row: wave w handles rows 2w, 2w+1
  int w = tid >> 6, lane = tid & 63;
#pragma unroll
  for (int rr = 2 * w; rr <= 2 * w + 1; rr++) {
    float a0 = ys[rr][lane], a1 = ys[rr][lane + 64];
    float s = a0 + a1, s2 = a0 * a0 + a1 * a1;
    for (int o = 32; o > 0; o >>= 1) {
      s += __shfl_xor(s, o, 64);
      s2 += __shfl_xor(s2, o, 64);
    }
    float mu = s * (1.f / 128.f);
    float var = s2 * (1.f / 128.f) - mu * mu;
    float rs = rsqrtf(var + 1e-5f);
    x4[(rbase + rr) * 128 + lane] = (a0 - mu) * rs * g1[lane] + be1[lane];
    x4[(rbase + rr) * 128 + lane + 64] = (a1 - mu) * rs * g1[lane + 64] + be1[lane + 64];
  }
}

// ---------------------------------------------------------------------------
// Kernel E: out0 = transpose(x4) : (N,L,C) -> (N,C,L). grid 128, block 256.
// ---------------------------------------------------------------------------
__global__ __launch_bounds__(256) void transpose_kernel(
    const float* __restrict__ x4, float* __restrict__ out) {
  __shared__ float ts[64][65];
  int bz = blockIdx.x;
  int n = bz >> 4;
  int tile = bz & 15;
  int lt = (tile >> 1) << 6;  // L/64 = 8 tiles
  int ct = (tile & 1) << 6;   // C/64 = 2 tiles
  int tid = threadIdx.x;

  for (int idx = tid; idx < 4096; idx += 256) {
    int lr = idx >> 6, cc = idx & 63;
    ts[lr][cc] = x4[((size_t)n * 512 + lt + lr) * 128 + ct + cc];
  }
  __syncthreads();
  for (int idx = tid; idx < 4096; idx += 256) {
    int cr = idx >> 6, lc = idx & 63;
    out[((size_t)n * 128 + ct + cr) * 512 + lt + lc] = ts[lc][cr];
  }
}

// ---------------------------------------------------------------------------
extern "C" void kernel_launch(void* const* d_in, const int* in_sizes, int n_in,
                              void* d_out, int out_size, void* d_ws, size_t ws_size,
                              hipStream_t stream) {
  const float* x   = (const float*)d_in[0];
  const float* Wx  = (const float*)d_in[1];
  const float* Wt  = (const float*)d_in[2];
  const float* bh  = (const float*)d_in[3];
  const float* Wa  = (const float*)d_in[4];
  const float* ba  = (const float*)d_in[5];
  const float* W0  = (const float*)d_in[6];
  const float* b0  = (const float*)d_in[7];
  const float* W1  = (const float*)d_in[8];
  const float* b1  = (const float*)d_in[9];
  const float* g0  = (const float*)d_in[10];
  const float* be0 = (const float*)d_in[11];
  const float* g1  = (const float*)d_in[12];
  const float* be1 = (const float*)d_in[13];

  float* outx = (float*)d_out;                  // N*C*L = 524288
  float* outa = outx + (size_t)524288;          // N*L*L = 2097152

  float* ws = (float*)d_ws;
  float* xt = ws;               // 524288
  float* q  = xt + 524288;      // 262144
  float* k  = q + 262144;       // 262144
  float* x2 = k + 262144;       // 524288
  float* x4 = x2 + 524288;      // 524288  (total 8 MB)

  qk_xt_kernel<<<64, 256, 0, stream>>>(x, Wx, Wt, q, k, xt);
  attn_kernel<<<2048, 128, 0, stream>>>(q, k, bh, Wa, ba, outa);
  av_ln_kernel<<<4096, 128, 0, stream>>>(outa, xt, g0, be0, x2);
  ffn_ln_kernel<<<512, 256, 0, stream>>>(x2, W0, b0, W1, b1, g1, be1, x4);
  transpose_kernel<<<128, 256, 0, stream>>>(x4, outx);
}

// Round 2
// 175.698 us; speedup vs baseline: 1.2624x; 1.2624x over previous
//
#include <hip/hip_runtime.h>
#include <cstddef>

// N=8, C=128, L=512, D=64, F=512, ATTN_W=64

// ---------------------------------------------------------------------------
// Kernel 1: transpose_in : x (N,C,L) -> xt (N,L,C). 64x64 LDS tiles.
// grid 128 (= N * L/64 * C/64), block 256.
// ---------------------------------------------------------------------------
__global__ __launch_bounds__(256) void transpose_in_kernel(
    const float* __restrict__ x, float* __restrict__ xt) {
  __shared__ float ts[64][65];
  int bz = blockIdx.x;
  int n = bz >> 4;
  int tile = bz & 15;
  int l0 = (tile >> 1) << 6;  // 8 l-tiles
  int c0 = (tile & 1) << 6;   // 2 c-tiles
  int tid = threadIdx.x;

  // read coalesced over l
  for (int idx = tid; idx < 4096; idx += 256) {
    int i = idx >> 6, j = idx & 63;  // i=c_rel, j=l_rel
    ts[i][j] = x[((size_t)n * 128 + c0 + i) * 512 + l0 + j];
  }
  __syncthreads();
  // write coalesced over c
  for (int idx = tid; idx < 4096; idx += 256) {
    int j = idx >> 6, i = idx & 63;  // j=l_rel, i=c_rel
    xt[((size_t)n * 512 + l0 + j) * 128 + c0 + i] = ts[i][j];
  }
}

// ---------------------------------------------------------------------------
// Kernel 2: q = xt@Wt, k = xt@Wx. Row-parallel: 8 rows/block, grid 512.
// Thread = 1 row x 4 outputs (f<64 -> q via Wt, f>=64 -> k via Wx).
// ---------------------------------------------------------------------------
__global__ __launch_bounds__(256) void qk_kernel(
    const float* __restrict__ xt, const float* __restrict__ Wt,
    const float* __restrict__ Wx, float* __restrict__ q,
    float* __restrict__ k) {
  __shared__ float xs[8][128];
  int tid = threadIdx.x;
  size_t rbase = (size_t)blockIdx.x * 8;

  for (int idx = tid; idx < 1024; idx += 256) {
    int r = idx >> 7, c = idx & 127;
    xs[r][c] = xt[(rbase + r) * 128 + c];
  }
  __syncthreads();

  int r = tid >> 5;           // 0..7
  int f0 = (tid & 31) << 2;   // 0..124
  const float* W = (f0 < 64) ? Wt : Wx;
  int ff = f0 & 63;
  float4 acc = make_float4(0.f, 0.f, 0.f, 0.f);
#pragma unroll 4
  for (int cc = 0; cc < 128; cc++) {
    float4 w = *(const float4*)(W + cc * 64 + ff);
    float xv = xs[r][cc];  // LDS broadcast (2 addrs/wave -> free)
    acc.x += xv * w.x; acc.y += xv * w.y;
    acc.z += xv * w.z; acc.w += xv * w.w;
  }
  float* dst = (f0 < 64) ? q : k;
  *(float4*)(dst + (rbase + r) * 64 + ff) = acc;
}

// ---------------------------------------------------------------------------
// Kernel 3: banded additive-attention scores + softmax -> a (N,L,L)
// grid 2048 (= N*L/2), block 128 (1 row per wave). In-band max valid:
// denominator >= 1, eps rescale error ~1e-5 << threshold.
// ---------------------------------------------------------------------------
__global__ __launch_bounds__(128) void attn_kernel(
    const float* __restrict__ q, const float* __restrict__ k,
    const float* __restrict__ bh, const float* __restrict__ Wa,
    const float* __restrict__ ba, float* __restrict__ a) {
  __shared__ float ks[2][64][65];
  __shared__ float qs[2][64];
  __shared__ float was[64];
  __shared__ float av[2][64];
  int tid = threadIdx.x;
  int w = tid >> 6, lane = tid & 63;
  int row = blockIdx.x * 2 + w;
  int n = row >> 9, i = row & 511;

  if (tid < 64) was[tid] = Wa[tid];
  qs[w][lane] = q[((size_t)n * 512 + i) * 64 + lane] + bh[lane];

  int jlo = i - 32;
  for (int it = 0; it < 64; it++) {
    int j = jlo + it;
    ks[w][it][lane] = (j >= 0 && j < 512) ? k[((size_t)n * 512 + j) * 64 + lane] : 0.f;
  }
  __syncthreads();

  int j = jlo + lane;
  bool valid = (j >= 0 && j < 512);
  float e = 0.f;
#pragma unroll 8
  for (int d = 0; d < 64; d++) {
    float hx = qs[w][d] + ks[w][lane][d];
    float ex2 = __expf(2.f * hx);
    float th = 1.f - 2.f * __builtin_amdgcn_rcpf(ex2 + 1.f);  // tanh
    e += was[d] * th;
  }
  e += ba[0];
  if (!valid) e = -1e30f;

  float m = e;
  for (int o = 32; o > 0; o >>= 1) m = fmaxf(m, __shfl_xor(m, o, 64));
  float ex = valid ? __expf(e - m) : 0.f;
  float s = ex;
  for (int o = 32; o > 0; o >>= 1) s += __shfl_xor(s, o, 64);
  float aval = ex / (s + 1e-6f);

  av[w][lane] = aval;
  __syncthreads();

  float* arow = a + ((size_t)n * 512 + i) * 512;
  for (int cb = 0; cb < 512; cb += 64) {
    int col = cb + lane;
    int jr = col - jlo;
    arow[col] = (jr >= 0 && jr < 64) ? av[w][jr] : 0.f;
  }
}

// ---------------------------------------------------------------------------
// Kernel 4: v = a @ xt (banded), x2 = LN0(v + xt). grid 4096, block 128.
// ---------------------------------------------------------------------------
__global__ __launch_bounds__(128) void av_ln_kernel(
    const float* __restrict__ a, const float* __restrict__ xt,
    const float* __restrict__ g0, const float* __restrict__ be0,
    float* __restrict__ x2) {
  __shared__ float as[64];
  __shared__ float red[4];
  int row = blockIdx.x;
  int n = row >> 9, i = row & 511;
  int c = threadIdx.x;
  int jlo = i - 32;

  if (c < 64) {
    int j = jlo + c;
    as[c] = (j >= 0 && j < 512) ? a[((size_t)n * 512 + i) * 512 + j] : 0.f;
  }
  __syncthreads();

  const float* xtn = xt + (size_t)n * 512 * 128;
  float acc = 0.f;
#pragma unroll 8
  for (int jr = 0; jr < 64; jr++) {
    int jc = min(max(jlo + jr, 0), 511);  // as[jr]==0 when OOB
    acc += as[jr] * xtn[jc * 128 + c];
  }
  float y = acc + xtn[i * 128 + c];

  float s = y, s2 = y * y;
  for (int o = 32; o > 0; o >>= 1) {
    s += __shfl_xor(s, o, 64);
    s2 += __shfl_xor(s2, o, 64);
  }
  int wid = c >> 6;
  if ((c & 63) == 0) { red[wid * 2] = s; red[wid * 2 + 1] = s2; }
  __syncthreads();
  float S = red[0] + red[2], S2 = red[1] + red[3];
  float mu = S * (1.f / 128.f);
  float var = S2 * (1.f / 128.f) - mu * mu;
  float rs = rsqrtf(var + 1e-5f);
  x2[(size_t)row * 128 + c] = (y - mu) * rs * g0[c] + be0[c];
}

// ---------------------------------------------------------------------------
// Kernel 5: FFN + residual + LN1. 8 rows/block, grid 512 (2 blocks/CU).
// GEMM1: thread = 4 rows x 4 f (strided), 16 FMA per K-step.
// GEMM2: K-split x4 across thread groups, LDS partial reduce.
// ---------------------------------------------------------------------------
__global__ __launch_bounds__(256) void ffn_ln_kernel(
    const float* __restrict__ x2, const float* __restrict__ W0,
    const float* __restrict__ b0, const float* __restrict__ W1,
    const float* __restrict__ b1, const float* __restrict__ g1,
    const float* __restrict__ be1, float* __restrict__ x4) {
  __shared__ float xst[128][12];   // [c][r] transposed x2 block, pad->12 (b128 ok)
  __shared__ float tst[512][12];   // [f][r] relu(GEMM1), transposed
  __shared__ float part[4][8][128];
  __shared__ float ys[8][128];
  int tid = threadIdx.x;
  size_t rbase = (size_t)blockIdx.x * 8;

  for (int idx = tid; idx < 1024; idx += 256) {
    int r = idx >> 7, c = idx & 127;
    xst[c][r] = x2[(rbase + r) * 128 + c];
  }
  __syncthreads();

  // GEMM1 + bias + relu -> tst
  {
    int fb = tid & 127;          // f = fb + 128*j
    int r0 = (tid >> 7) << 2;    // 0 or 4
    float acc[4][4];
#pragma unroll
    for (int i = 0; i < 4; i++)
#pragma unroll
      for (int jj = 0; jj < 4; jj++) acc[i][jj] = 0.f;
#pragma unroll 4
    for (int cc = 0; cc < 128; cc++) {
      float4 xv = *(const float4*)(&xst[cc][r0]);  // broadcast
      float w0 = W0[cc * 512 + fb];
      float w1 = W0[cc * 512 + fb + 128];
      float w2 = W0[cc * 512 + fb + 256];
      float w3 = W0[cc * 512 + fb + 384];
      acc[0][0] += xv.x * w0; acc[1][0] += xv.y * w0; acc[2][0] += xv.z * w0; acc[3][0] += xv.w * w0;
      acc[0][1] += xv.x * w1; acc[1][1] += xv.y * w1; acc[2][1] += xv.z * w1; acc[3][1] += xv.w * w1;
      acc[0][2] += xv.x * w2; acc[1][2] += xv.y * w2; acc[2][2] += xv.z * w2; acc[3][2] += xv.w * w2;
      acc[0][3] += xv.x * w3; acc[1][3] += xv.y * w3; acc[2][3] += xv.z * w3; acc[3][3] += xv.w * w3;
    }
#pragma unroll
    for (int jj = 0; jj < 4; jj++) {
      int f = fb + 128 * jj;
      float bb = b0[f];
      float4 v = make_float4(fmaxf(acc[0][jj] + bb, 0.f), fmaxf(acc[1][jj] + bb, 0.f),
                             fmaxf(acc[2][jj] + bb, 0.f), fmaxf(acc[3][jj] + bb, 0.f));
      *(float4*)(&tst[f][r0]) = v;
    }
  }
  __syncthreads();

  // GEMM2 (K-split x4) -> part
  {
    int c0 = (tid & 31) << 2;         // 0..124
    int r0 = ((tid >> 5) & 1) << 2;   // 0 or 4
    int kq = tid >> 6;                // 0..3
    float acc[4][4];
#pragma unroll
    for (int i = 0; i < 4; i++)
#pragma unroll
      for (int jj = 0; jj < 4; jj++) acc[i][jj] = 0.f;
    const float* W1p = W1 + (size_t)kq * 128 * 128;
    const float(*tstp)[12] = &tst[kq * 128];
#pragma unroll 4
    for (int t = 0; t < 128; t++) {
      float4 w = *(const float4*)(W1p + t * 128 + c0);
      float4 tv = *(const float4*)(&tstp[t][r0]);  // broadcast
      acc[0][0] += tv.x * w.x; acc[0][1] += tv.x * w.y; acc[0][2] += tv.x * w.z; acc[0][3] += tv.x * w.w;
      acc[1][0] += tv.y * w.x; acc[1][1] += tv.y * w.y; acc[1][2] += tv.y * w.z; acc[1][3] += tv.y * w.w;
      acc[2][0] += tv.z * w.x; acc[2][1] += tv.z * w.y; acc[2][2] += tv.z * w.z; acc[2][3] += tv.z * w.w;
      acc[3][0] += tv.w * w.x; acc[3][1] += tv.w * w.y; acc[3][2] += tv.w * w.z; acc[3][3] += tv.w * w.w;
    }
#pragma unroll
    for (int i = 0; i < 4; i++) {
      *(float4*)(&part[kq][r0 + i][c0]) =
          make_float4(acc[i][0], acc[i][1], acc[i][2], acc[i][3]);
    }
  }
  __syncthreads();

  // reduce K-partials + bias + residual
  for (int idx = tid; idx < 1024; idx += 256) {
    int r = idx >> 7, c = idx & 127;
    float v = part[0][r][c] + part[1][r][c] + part[2][r][c] + part[3][r][c] +
              b1[c] + xst[c][r];
    ys[r][c] = v;
  }
  __syncthreads();

  // LN1: wave w handles rows 2w, 2w+1
  int w = tid >> 6, lane = tid & 63;
#pragma unroll
  for (int rr = 2 * w; rr <= 2 * w + 1; rr++) {
    float a0 = ys[rr][lane], a1 = ys[rr][lane + 64];
    float s = a0 + a1, s2 = a0 * a0 + a1 * a1;
    for (int o = 32; o > 0; o >>= 1) {
      s += __shfl_xor(s, o, 64);
      s2 += __shfl_xor(s2, o, 64);
    }
    float mu = s * (1.f / 128.f);
    float var = s2 * (1.f / 128.f) - mu * mu;
    float rs = rsqrtf(var + 1e-5f);
    x4[(rbase + rr) * 128 + lane] = (a0 - mu) * rs * g1[lane] + be1[lane];
    x4[(rbase + rr) * 128 + lane + 64] = (a1 - mu) * rs * g1[lane + 64] + be1[lane + 64];
  }
}

// ---------------------------------------------------------------------------
// Kernel 6: out0 = transpose(x4) : (N,L,C) -> (N,C,L). grid 128, block 256.
// ---------------------------------------------------------------------------
__global__ __launch_bounds__(256) void transpose_kernel(
    const float* __restrict__ x4, float* __restrict__ out) {
  __shared__ float ts[64][65];
  int bz = blockIdx.x;
  int n = bz >> 4;
  int tile = bz & 15;
  int lt = (tile >> 1) << 6;
  int ct = (tile & 1) << 6;
  int tid = threadIdx.x;

  for (int idx = tid; idx < 4096; idx += 256) {
    int lr = idx >> 6, cc = idx & 63;
    ts[lr][cc] = x4[((size_t)n * 512 + lt + lr) * 128 + ct + cc];
  }
  __syncthreads();
  for (int idx = tid; idx < 4096; idx += 256) {
    int cr = idx >> 6, lc = idx & 63;
    out[((size_t)n * 128 + ct + cr) * 512 + lt + lc] = ts[lc][cr];
  }
}

// ---------------------------------------------------------------------------
extern "C" void kernel_launch(void* const* d_in, const int* in_sizes, int n_in,
                              void* d_out, int out_size, void* d_ws, size_t ws_size,
                              hipStream_t stream) {
  const float* x   = (const float*)d_in[0];
  const float* Wx  = (const float*)d_in[1];
  const float* Wt  = (const float*)d_in[2];
  const float* bh  = (const float*)d_in[3];
  const float* Wa  = (const float*)d_in[4];
  const float* ba  = (const float*)d_in[5];
  const float* W0  = (const float*)d_in[6];
  const float* b0  = (const float*)d_in[7];
  const float* W1  = (const float*)d_in[8];
  const float* b1  = (const float*)d_in[9];
  const float* g0  = (const float*)d_in[10];
  const float* be0 = (const float*)d_in[11];
  const float* g1  = (const float*)d_in[12];
  const float* be1 = (const float*)d_in[13];

  float* outx = (float*)d_out;           // N*C*L = 524288
  float* outa = outx + (size_t)524288;   // N*L*L = 2097152

  float* ws = (float*)d_ws;
  float* xt = ws;              // 524288
  float* q  = xt + 524288;     // 262144
  float* k  = q + 262144;      // 262144
  float* x2 = k + 262144;      // 524288
  float* x4 = x2 + 524288;     // 524288

  transpose_in_kernel<<<128, 256, 0, stream>>>(x, xt);
  qk_kernel<<<512, 256, 0, stream>>>(xt, Wt, Wx, q, k);
  attn_kernel<<<2048, 128, 0, stream>>>(q, k, bh, Wa, ba, outa);
  av_ln_kernel<<<4096, 128, 0, stream>>>(outa, xt, g0, be0, x2);
  ffn_ln_kernel<<<512, 256, 0, stream>>>(x2, W0, b0, W1, b1, g1, be1, x4);
  transpose_kernel<<<128, 256, 0, stream>>>(x4, outx);
}

// Round 3
// 142.095 us; speedup vs baseline: 1.5609x; 1.2365x over previous
//
#include <hip/hip_runtime.h>
#include <cstddef>

// N=8, C=128, L=512, D=64, F=512, ATTN_W=64

// ---------------------------------------------------------------------------
// Kernel 1: prep = transpose_in + q/k projection.
// grid 256 (= N * L/16), block 256. x tile (128c x 16l) staged in LDS once;
// used for both the xt write and the q/k GEMM.
// ---------------------------------------------------------------------------
__global__ __launch_bounds__(256) void prep_kernel(
    const float* __restrict__ x, const float* __restrict__ Wt,
    const float* __restrict__ Wx, float* __restrict__ xt,
    float* __restrict__ q, float* __restrict__ k) {
  __shared__ float xs[128][17];  // [c][l_rel], pad 17: conflict-light
  int tid = threadIdx.x;
  int n = blockIdx.x >> 5;
  int l0 = (blockIdx.x & 31) << 4;

  // load x tile: 128 rows x 4 float4
  for (int idx = tid; idx < 512; idx += 256) {
    int c = idx >> 2, v = idx & 3;
    float4 d4 = *(const float4*)(x + ((size_t)n * 128 + c) * 512 + l0 + 4 * v);
    xs[c][4 * v + 0] = d4.x; xs[c][4 * v + 1] = d4.y;
    xs[c][4 * v + 2] = d4.z; xs[c][4 * v + 3] = d4.w;
  }
  __syncthreads();

  // write xt (N,L,C), coalesced over c
  for (int idx = tid; idx < 2048; idx += 256) {
    int c = idx & 127, jj = idx >> 7;
    xt[((size_t)n * 512 + l0 + jj) * 128 + c] = xs[c][jj];
  }

  // q/k GEMM: thread = 1 row x 8 outputs of one matrix
  int r = tid >> 4;                     // 0..15
  int g = tid & 15;                     // 0..7 -> q, 8..15 -> k
  const float* W = (g < 8) ? Wt : Wx;
  float* dst = (g < 8) ? q : k;
  int f0 = (g & 7) << 3;
  float acc[8];
#pragma unroll
  for (int i = 0; i < 8; i++) acc[i] = 0.f;
#pragma unroll 4
  for (int cc = 0; cc < 128; cc++) {
    float xv = xs[cc][r];  // 16 distinct addrs/wave, bank-disjoint
    float4 w0 = *(const float4*)(W + cc * 64 + f0);
    float4 w1 = *(const float4*)(W + cc * 64 + f0 + 4);
    acc[0] += xv * w0.x; acc[1] += xv * w0.y; acc[2] += xv * w0.z; acc[3] += xv * w0.w;
    acc[4] += xv * w1.x; acc[5] += xv * w1.y; acc[6] += xv * w1.z; acc[7] += xv * w1.w;
  }
  float* dp = dst + ((size_t)n * 512 + l0 + r) * 64 + f0;
  *(float4*)dp = make_float4(acc[0], acc[1], acc[2], acc[3]);
  *(float4*)(dp + 4) = make_float4(acc[4], acc[5], acc[6], acc[7]);
}

// ---------------------------------------------------------------------------
// Kernel 2: banded additive-attention scores + softmax -> a (N,L,L)
// grid 1024 (= N * L/4), block 256 (4 waves; wave w = row i0+w).
// ONE shared k-window of 67 rows per block (vs 64 rows per ROW before):
// 16x less staging, LDS 19.7 KB -> 4 blocks/CU resident (50% occ).
// In-band max valid: denom >= 1, eps rescale error ~1e-5 << threshold.
// ---------------------------------------------------------------------------
__global__ __launch_bounds__(256) void attn_kernel(
    const float* __restrict__ q, const float* __restrict__ k,
    const float* __restrict__ bh, const float* __restrict__ Wa,
    const float* __restrict__ ba, float* __restrict__ a) {
  __shared__ float ks[67][65];  // [win_row][d], stride 65 -> 2-way (free)
  __shared__ float qs[4][64];
  __shared__ float was[64];
  __shared__ float av[4][64];
  int tid = threadIdx.x;
  int w = tid >> 6, lane = tid & 63;
  int n = blockIdx.x >> 7;
  int i0 = (blockIdx.x & 127) << 2;
  int i = i0 + w;
  int jlo0 = i0 - 32;

  if (tid < 64) was[tid] = Wa[tid];
  qs[w][lane] = q[((size_t)n * 512 + i) * 64 + lane] + bh[lane];

  // cooperative staging: wave w stages window rows w, w+4, ...
  for (int row = w; row < 67; row += 4) {
    int j = jlo0 + row;
    ks[row][lane] = (j >= 0 && j < 512) ? k[((size_t)n * 512 + j) * 64 + lane] : 0.f;
  }
  __syncthreads();

  int j = jlo0 + w + lane;  // this lane's key index
  bool valid = (j >= 0 && j < 512);
  const float* krow = &ks[w + lane][0];
  float e = 0.f;
#pragma unroll 8
  for (int d = 0; d < 64; d++) {
    float hx = qs[w][d] + krow[d];
    float ex2 = __expf(2.f * hx);
    float th = 1.f - 2.f * __builtin_amdgcn_rcpf(ex2 + 1.f);  // tanh
    e += was[d] * th;
  }
  e += ba[0];
  if (!valid) e = -1e30f;

  float m = e;
  for (int o = 32; o > 0; o >>= 1) m = fmaxf(m, __shfl_xor(m, o, 64));
  float ex = valid ? __expf(e - m) : 0.f;
  float s = ex;
  for (int o = 32; o > 0; o >>= 1) s += __shfl_xor(s, o, 64);
  av[w][lane] = ex / (s + 1e-6f);
  __syncthreads();

  // write full a row (zeros outside band), float4
  float* arow = a + ((size_t)n * 512 + i) * 512;
  int jlo = i - 32;
#pragma unroll
  for (int t = 0; t < 2; t++) {
    int col0 = 4 * lane + 256 * t;
    float4 v;
    {
      int jr = col0 + 0 - jlo; int jc = min(max(jr, 0), 63);
      v.x = (jr >= 0 && jr < 64) ? av[w][jc] : 0.f;
    }
    {
      int jr = col0 + 1 - jlo; int jc = min(max(jr, 0), 63);
      v.y = (jr >= 0 && jr < 64) ? av[w][jc] : 0.f;
    }
    {
      int jr = col0 + 2 - jlo; int jc = min(max(jr, 0), 63);
      v.z = (jr >= 0 && jr < 64) ? av[w][jc] : 0.f;
    }
    {
      int jr = col0 + 3 - jlo; int jc = min(max(jr, 0), 63);
      v.w = (jr >= 0 && jr < 64) ? av[w][jc] : 0.f;
    }
    *(float4*)(arow + col0) = v;
  }
}

// ---------------------------------------------------------------------------
// Kernel 3: v = a @ xt (banded), x2 = LN0(v + xt). grid 4096, block 128.
// ---------------------------------------------------------------------------
__global__ __launch_bounds__(128) void av_ln_kernel(
    const float* __restrict__ a, const float* __restrict__ xt,
    const float* __restrict__ g0, const float* __restrict__ be0,
    float* __restrict__ x2) {
  __shared__ float as[64];
  __shared__ float red[4];
  int row = blockIdx.x;
  int n = row >> 9, i = row & 511;
  int c = threadIdx.x;
  int jlo = i - 32;

  if (c < 64) {
    int j = jlo + c;
    as[c] = (j >= 0 && j < 512) ? a[((size_t)n * 512 + i) * 512 + j] : 0.f;
  }
  __syncthreads();

  const float* xtn = xt + (size_t)n * 512 * 128;
  float acc = 0.f;
#pragma unroll 8
  for (int jr = 0; jr < 64; jr++) {
    int jc = min(max(jlo + jr, 0), 511);  // as[jr]==0 when OOB
    acc += as[jr] * xtn[jc * 128 + c];
  }
  float y = acc + xtn[i * 128 + c];

  float s = y, s2 = y * y;
  for (int o = 32; o > 0; o >>= 1) {
    s += __shfl_xor(s, o, 64);
    s2 += __shfl_xor(s2, o, 64);
  }
  int wid = c >> 6;
  if ((c & 63) == 0) { red[wid * 2] = s; red[wid * 2 + 1] = s2; }
  __syncthreads();
  float S = red[0] + red[2], S2 = red[1] + red[3];
  float mu = S * (1.f / 128.f);
  float var = S2 * (1.f / 128.f) - mu * mu;
  float rs = rsqrtf(var + 1e-5f);
  x2[(size_t)row * 128 + c] = (y - mu) * rs * g0[c] + be0[c];
}

// ---------------------------------------------------------------------------
// Kernel 4: FFN + residual + LN1 + transposed write -> out (N,C,L).
// 8 rows/block, grid 512. GEMM1: 4r x 4f per thread. GEMM2: K-split x4.
// Final transpose fused (LN result already in LDS).
// ---------------------------------------------------------------------------
__global__ __launch_bounds__(256) void ffn_ln_kernel(
    const float* __restrict__ x2, const float* __restrict__ W0,
    const float* __restrict__ b0, const float* __restrict__ W1,
    const float* __restrict__ b1, const float* __restrict__ g1,
    const float* __restrict__ be1, float* __restrict__ out) {
  __shared__ float xst[128][12];   // [c][r] transposed x2 block
  __shared__ float tst[512][12];   // [f][r] relu(GEMM1), transposed
  __shared__ float part[4][8][128];
  __shared__ float ys[8][128];
  int tid = threadIdx.x;
  size_t rbase = (size_t)blockIdx.x * 8;

  for (int idx = tid; idx < 1024; idx += 256) {
    int r = idx >> 7, c = idx & 127;
    xst[c][r] = x2[(rbase + r) * 128 + c];
  }
  __syncthreads();

  // GEMM1 + bias + relu -> tst
  {
    int fb = tid & 127;
    int r0 = (tid >> 7) << 2;
    float acc[4][4];
#pragma unroll
    for (int i = 0; i < 4; i++)
#pragma unroll
      for (int jj = 0; jj < 4; jj++) acc[i][jj] = 0.f;
#pragma unroll 4
    for (int cc = 0; cc < 128; cc++) {
      float4 xv = *(const float4*)(&xst[cc][r0]);
      float w0 = W0[cc * 512 + fb];
      float w1 = W0[cc * 512 + fb + 128];
      float w2 = W0[cc * 512 + fb + 256];
      float w3 = W0[cc * 512 + fb + 384];
      acc[0][0] += xv.x * w0; acc[1][0] += xv.y * w0; acc[2][0] += xv.z * w0; acc[3][0] += xv.w * w0;
      acc[0][1] += xv.x * w1; acc[1][1] += xv.y * w1; acc[2][1] += xv.z * w1; acc[3][1] += xv.w * w1;
      acc[0][2] += xv.x * w2; acc[1][2] += xv.y * w2; acc[2][2] += xv.z * w2; acc[3][2] += xv.w * w2;
      acc[0][3] += xv.x * w3; acc[1][3] += xv.y * w3; acc[2][3] += xv.z * w3; acc[3][3] += xv.w * w3;
    }
#pragma unroll
    for (int jj = 0; jj < 4; jj++) {
      int f = fb + 128 * jj;
      float bb = b0[f];
      float4 v = make_float4(fmaxf(acc[0][jj] + bb, 0.f), fmaxf(acc[1][jj] + bb, 0.f),
                             fmaxf(acc[2][jj] + bb, 0.f), fmaxf(acc[3][jj] + bb, 0.f));
      *(float4*)(&tst[f][r0]) = v;
    }
  }
  __syncthreads();

  // GEMM2 (K-split x4) -> part
  {
    int c0 = (tid & 31) << 2;
    int r0 = ((tid >> 5) & 1) << 2;
    int kq = tid >> 6;
    float acc[4][4];
#pragma unroll
    for (int i = 0; i < 4; i++)
#pragma unroll
      for (int jj = 0; jj < 4; jj++) acc[i][jj] = 0.f;
    const float* W1p = W1 + (size_t)kq * 128 * 128;
    const float(*tstp)[12] = &tst[kq * 128];
#pragma unroll 4
    for (int t = 0; t < 128; t++) {
      float4 w = *(const float4*)(W1p + t * 128 + c0);
      float4 tv = *(const float4*)(&tstp[t][r0]);
      acc[0][0] += tv.x * w.x; acc[0][1] += tv.x * w.y; acc[0][2] += tv.x * w.z; acc[0][3] += tv.x * w.w;
      acc[1][0] += tv.y * w.x; acc[1][1] += tv.y * w.y; acc[1][2] += tv.y * w.z; acc[1][3] += tv.y * w.w;
      acc[2][0] += tv.z * w.x; acc[2][1] += tv.z * w.y; acc[2][2] += tv.z * w.z; acc[2][3] += tv.z * w.w;
      acc[3][0] += tv.w * w.x; acc[3][1] += tv.w * w.y; acc[3][2] += tv.w * w.z; acc[3][3] += tv.w * w.w;
    }
#pragma unroll
    for (int i = 0; i < 4; i++) {
      *(float4*)(&part[kq][r0 + i][c0]) =
          make_float4(acc[i][0], acc[i][1], acc[i][2], acc[i][3]);
    }
  }
  __syncthreads();

  // reduce K-partials + bias + residual
  for (int idx = tid; idx < 1024; idx += 256) {
    int r = idx >> 7, c = idx & 127;
    ys[r][c] = part[0][r][c] + part[1][r][c] + part[2][r][c] + part[3][r][c] +
               b1[c] + xst[c][r];
  }
  __syncthreads();

  // LN1 in place (each lane reads only its own 2 elements)
  int w = tid >> 6, lane = tid & 63;
#pragma unroll
  for (int rr = 2 * w; rr <= 2 * w + 1; rr++) {
    float a0 = ys[rr][lane], a1 = ys[rr][lane + 64];
    float s = a0 + a1, s2 = a0 * a0 + a1 * a1;
    for (int o = 32; o > 0; o >>= 1) {
      s += __shfl_xor(s, o, 64);
      s2 += __shfl_xor(s2, o, 64);
    }
    float mu = s * (1.f / 128.f);
    float var = s2 * (1.f / 128.f) - mu * mu;
    float rs = rsqrtf(var + 1e-5f);
    ys[rr][lane] = (a0 - mu) * rs * g1[lane] + be1[lane];
    ys[rr][lane + 64] = (a1 - mu) * rs * g1[lane + 64] + be1[lane + 64];
  }
  __syncthreads();

  // transposed write: out (N,C,L); 8 consecutive l per c
  {
    int c = tid >> 1, t = tid & 1;
    int n = (int)(rbase >> 9);
    int l0 = (int)(rbase & 511);
    float4 v = make_float4(ys[4 * t + 0][c], ys[4 * t + 1][c],
                           ys[4 * t + 2][c], ys[4 * t + 3][c]);
    *(float4*)(out + ((size_t)n * 128 + c) * 512 + l0 + 4 * t) = v;
  }
}

// ---------------------------------------------------------------------------
extern "C" void kernel_launch(void* const* d_in, const int* in_sizes, int n_in,
                              void* d_out, int out_size, void* d_ws, size_t ws_size,
                              hipStream_t stream) {
  const float* x   = (const float*)d_in[0];
  const float* Wx  = (const float*)d_in[1];
  const float* Wt  = (const float*)d_in[2];
  const float* bh  = (const float*)d_in[3];
  const float* Wa  = (const float*)d_in[4];
  const float* ba  = (const float*)d_in[5];
  const float* W0  = (const float*)d_in[6];
  const float* b0  = (const float*)d_in[7];
  const float* W1  = (const float*)d_in[8];
  const float* b1  = (const float*)d_in[9];
  const float* g0  = (const float*)d_in[10];
  const float* be0 = (const float*)d_in[11];
  const float* g1  = (const float*)d_in[12];
  const float* be1 = (const float*)d_in[13];

  float* outx = (float*)d_out;           // N*C*L = 524288
  float* outa = outx + (size_t)524288;   // N*L*L = 2097152

  float* ws = (float*)d_ws;
  float* xt = ws;              // 524288
  float* q  = xt + 524288;     // 262144
  float* k  = q + 262144;      // 262144
  float* x2 = k + 262144;      // 524288

  prep_kernel<<<256, 256, 0, stream>>>(x, Wt, Wx, xt, q, k);
  attn_kernel<<<1024, 256, 0, stream>>>(q, k, bh, Wa, ba, outa);
  av_ln_kernel<<<4096, 128, 0, stream>>>(outa, xt, g0, be0, x2);
  ffn_ln_kernel<<<512, 256, 0, stream>>>(x2, W0, b0, W1, b1, g1, be1, outx);
}